// Round 3
// baseline (278.184 us; speedup 1.0000x reference)
//
#include <hip/hip_runtime.h>
#include <math.h>

#define D 64
#define K 512
#define ROWS 131072       // 32*64*64
#define NELEM (ROWS * D)  // 8388608

// ws layout: [0,8) double loss accumulator

__global__ __launch_bounds__(256) void vq_main(const float* __restrict__ x,
                                               const float* __restrict__ cb,
                                               float* __restrict__ out,
                                               double* __restrict__ loss_acc) {
#pragma clang fp contract(off)
    __shared__ float ldsB[K];     // B_j = sum_k cb[k][j]^2, numpy order
    __shared__ float wavesum[4];

    const int tid = threadIdx.x;
    const size_t row = (size_t)blockIdx.x * 256 + tid;

    // ---- B = np.sum(codebook**2, axis=0): sequential over k ascending ----
    #pragma unroll
    for (int rep = 0; rep < 2; ++rep) {
        int j = tid + rep * 256;
        float c0 = cb[j];
        float b = c0 * c0;
        for (int k = 1; k < D; ++k) {
            float ck = cb[k * K + j];
            b = b + ck * ck;              // separate mul+add (contract off)
        }
        ldsB[j] = b;
    }

    // ---- load my row into registers ----
    float xr[D];
    {
        const float4* xv = (const float4*)(x + row * D);
        #pragma unroll
        for (int i = 0; i < D / 4; ++i) {
            float4 v = xv[i];
            xr[4*i+0] = v.x; xr[4*i+1] = v.y; xr[4*i+2] = v.z; xr[4*i+3] = v.w;
        }
    }

    // ---- A = np.sum(x**2, axis=1): numpy pairwise_sum n=64 emulation ----
    float A0;
    {
        float r[8];
        #pragma unroll
        for (int l = 0; l < 8; ++l) r[l] = xr[l] * xr[l];
        #pragma unroll
        for (int m = 1; m < 8; ++m) {
            #pragma unroll
            for (int l = 0; l < 8; ++l) {
                float q = xr[8*m + l] * xr[8*m + l];
                r[l] = r[l] + q;
            }
        }
        A0 = ((r[0] + r[1]) + (r[2] + r[3])) + ((r[4] + r[5]) + (r[6] + r[7]));
    }

    __syncthreads();   // ldsB ready

    float m0 = INFINITY;
    int i0 = 0;

    // ---- distance loop: codebook via wave-uniform (scalar) loads ----
    for (int j0 = 0; j0 < K; j0 += 8) {
        float a[8];
        #pragma unroll
        for (int k = 0; k < 8; ++k) a[k] = 0.f;
        #pragma unroll
        for (int d = 0; d < D; ++d) {
            // loop-uniform address -> s_load_dwordx8 (scalar cache broadcast)
            const float* crow = cb + d * K + j0;
            float xd = xr[d];
            a[0] = fmaf(xd, crow[0], a[0]);
            a[1] = fmaf(xd, crow[1], a[1]);
            a[2] = fmaf(xd, crow[2], a[2]);
            a[3] = fmaf(xd, crow[3], a[3]);
            a[4] = fmaf(xd, crow[4], a[4]);
            a[5] = fmaf(xd, crow[5], a[5]);
            a[6] = fmaf(xd, crow[6], a[6]);
            a[7] = fmaf(xd, crow[7], a[7]);
        }
        #pragma unroll
        for (int k = 0; k < 8; ++k) {
            int j = j0 + k;
            float Bj = ldsB[j];            // wave-uniform LDS broadcast
            float t0 = 2.0f * a[k];        // exact; == (2*x)@cb fma chain
            float s0 = A0 + Bj;
            float d0 = s0 - t0;            // numpy: (A+B) - 2M, contract off
            if (d0 < m0) { m0 = d0; i0 = j; }   // strict <, ascending j
        }
    }

    // ---- gather codebook column i0, write out, accumulate loss ----
    float lsum = 0.f;
    float4* o4 = (float4*)(out + row * D);
    #pragma unroll
    for (int d0 = 0; d0 < D; d0 += 4) {
        float q0 = cb[(d0+0)*K + i0], q1 = cb[(d0+1)*K + i0];
        float q2 = cb[(d0+2)*K + i0], q3 = cb[(d0+3)*K + i0];
        float e0 = q0 - xr[d0+0], e1 = q1 - xr[d0+1];
        float e2 = q2 - xr[d0+2], e3 = q3 - xr[d0+3];
        lsum += e0*e0 + e1*e1 + e2*e2 + e3*e3;
        o4[d0/4] = make_float4(q0, q1, q2, q3);
    }

    #pragma unroll
    for (int off = 32; off > 0; off >>= 1) lsum += __shfl_down(lsum, off);
    int lane = tid & 63, wave = tid >> 6;
    if (lane == 0) wavesum[wave] = lsum;
    __syncthreads();
    if (tid == 0) {
        double tot = (double)wavesum[0] + (double)wavesum[1]
                   + (double)wavesum[2] + (double)wavesum[3];
        atomicAdd(loss_acc, tot);
    }
}

__global__ void vq_finalize(const double* __restrict__ acc, float* __restrict__ out) {
    // loss = (1 + beta) * mean((q - x)^2), beta = 0.25
    out[NELEM] = (float)(acc[0] * (1.25 / (double)NELEM));
}

extern "C" void kernel_launch(void* const* d_in, const int* in_sizes, int n_in,
                              void* d_out, int out_size, void* d_ws, size_t ws_size,
                              hipStream_t stream) {
    const float* x  = (const float*)d_in[0];   // [32,64,64,64] fp32
    const float* cb = (const float*)d_in[1];   // [64,512] fp32
    float* out = (float*)d_out;                // [8388608] out + [1] loss
    double* loss_acc = (double*)d_ws;

    hipMemsetAsync(d_ws, 0, 16, stream);
    vq_main<<<ROWS / 256, 256, 0, stream>>>(x, cb, out, loss_acc);
    vq_finalize<<<1, 1, 0, stream>>>(loss_acc, out);
}

// Round 4
// 186.683 us; speedup vs baseline: 1.4901x; 1.4901x over previous
//
#include <hip/hip_runtime.h>
#include <math.h>

#define D 64
#define K 512
#define ROWS 131072       // 32*64*64
#define NELEM (ROWS * D)  // 8388608
#define T_FLAG 6e-5f      // certainty gap threshold (cert. error ~2e-5, 3x margin)
#define FLAGBIT (1 << 30)

typedef _Float16 half8 __attribute__((ext_vector_type(8)));
typedef float floatx4 __attribute__((ext_vector_type(4)));

// ws layout: [0,8) double loss acc ; [8,12) int worklist counter ; [16,16+512KB) worklist

// ---------------------------------------------------------------------------
// Kernel A: fp16-split MFMA distance filter. 512 thr = 8 waves, 16 rows/wave.
// Certain rows (approx gap >= T_FLAG): gather + loss here. Else -> worklist.
// ---------------------------------------------------------------------------
__global__ __launch_bounds__(512) void vq_mfma(const float* __restrict__ x,
                                               const float* __restrict__ cb,
                                               float* __restrict__ out,
                                               double* __restrict__ loss_acc,
                                               int* __restrict__ counter,
                                               int* __restrict__ worklist) {
    __shared__ _Float16 cbH[32768];   // B-frags, fragment-order, 64 KB
    __shared__ _Float16 cbL[32768];   // 64 KB
    __shared__ float ldsB[K];         // numpy-order column norms
    __shared__ int rowinfo[8][16];
    __shared__ float wavesum[8];

    const int tid = threadIdx.x;
    const int lane = tid & 63;
    const int w = tid >> 6;
    const int quad = lane >> 4;
    const int nn = lane & 15;

    // ---- stage codebook as scaled fp16 hi/lo in MFMA B-fragment order ----
    // frag def (16x16x32): lane l holds B[k = (l>>4)*8 + j][n = l&15], j<8.
    for (int idx = tid; idx < 32768; idx += 512) {
        int k = idx >> 9, n = idx & 511;
        float c = cb[idx];                       // cb[k][n], coalesced
        float t = c * 4096.0f;                   // 2^12, exact
        _Float16 ch = (_Float16)t;               // scale 2^12, fp16-normal
        float r = t - (float)ch;                 // exact
        _Float16 cl = (_Float16)(r * 4096.0f);   // scale 2^24
        int off = (((n >> 4) * 2 + (k >> 5)) * 64
                   + ((k >> 3) & 3) * 16 + (n & 15)) * 8 + (k & 7);
        cbH[off] = ch;
        cbL[off] = cl;
    }
    // ---- B_j = np.sum(cb**2, axis=0): sequential k ascending ----
    {
#pragma clang fp contract(off)
        int j = tid;
        if (j < K) {
            float b = 0.f;
            for (int k = 0; k < D; ++k) { float c = cb[k * K + j]; b = b + c * c; }
            ldsB[j] = b;
        }
    }
    __syncthreads();

    const int rowBase = blockIdx.x * 128 + w * 16;

    // ---- x A-frags: lane holds A[m=nn][k=quad*8+j], scaled fp16 hi/lo ----
    half8 xh[2], xl[2];
    #pragma unroll
    for (int s = 0; s < 2; ++s) {
        const float* xp = x + (size_t)(rowBase + nn) * D + s * 32 + quad * 8;
        float4 v0 = *(const float4*)xp;
        float4 v1 = *(const float4*)(xp + 4);
        float vv[8] = {v0.x, v0.y, v0.z, v0.w, v1.x, v1.y, v1.z, v1.w};
        #pragma unroll
        for (int j = 0; j < 8; ++j) {
            float t = vv[j] * 256.0f;            // 2^8, exact
            _Float16 h = (_Float16)t;
            float r = t - (float)h;              // exact
            xh[s][j] = h;                        // scale 2^8
            xl[s][j] = (_Float16)(r * 4096.0f);  // scale 2^20
        }
    }

    float m1[4] = {INFINITY, INFINITY, INFINITY, INFINITY};
    float m2[4] = {INFINITY, INFINITY, INFINITY, INFINITY};
    int   i1[4] = {0, 0, 0, 0};

    #pragma unroll 4
    for (int t = 0; t < 32; ++t) {
        floatx4 acc1 = {0.f, 0.f, 0.f, 0.f};
        floatx4 acc2 = {0.f, 0.f, 0.f, 0.f};
        #pragma unroll
        for (int s = 0; s < 2; ++s) {
            int fo = (t * 2 + s) * 64 + lane;    // half8 index -> lane-linear b128
            half8 bh = ((const half8*)cbH)[fo];
            half8 bl = ((const half8*)cbL)[fo];
            acc2 = __builtin_amdgcn_mfma_f32_16x16x32_f16(xl[s], bh, acc2, 0, 0, 0);
            acc2 = __builtin_amdgcn_mfma_f32_16x16x32_f16(xh[s], bl, acc2, 0, 0, 0);
            acc1 = __builtin_amdgcn_mfma_f32_16x16x32_f16(xh[s], bh, acc1, 0, 0, 0);
        }
        int col = t * 16 + nn;                   // C/D: col = lane&15
        float Bj = ldsB[col];
        #pragma unroll
        for (int r = 0; r < 4; ++r) {            // row = quad*4 + r
            float M = fmaf(0x1p-32f, acc2[r], 0x1p-20f * acc1[r]);
            float g = fmaf(-2.0f, M, Bj);        // ~ d_np - A
            bool c1 = g < m1[r];
            bool c2 = g < m2[r];
            m2[r] = c1 ? m1[r] : (c2 ? g : m2[r]);
            m1[r] = c1 ? g : m1[r];
            i1[r] = c1 ? col : i1[r];
        }
    }

    // ---- merge best-2 across the 16 col-lanes (butterfly, low 4 lane bits) ----
    #pragma unroll
    for (int dlt = 1; dlt < 16; dlt <<= 1) {
        #pragma unroll
        for (int r = 0; r < 4; ++r) {
            float om1 = __shfl_xor(m1[r], dlt);
            int   oi1 = __shfl_xor(i1[r], dlt);
            float om2 = __shfl_xor(m2[r], dlt);
            bool ofirst = (om1 < m1[r]) || (om1 == m1[r] && oi1 < i1[r]);
            float l1   = ofirst ? m1[r] : om1;
            float cand = ofirst ? om2 : m2[r];
            m1[r] = ofirst ? om1 : m1[r];
            i1[r] = ofirst ? oi1 : i1[r];
            m2[r] = fminf(cand, l1);
        }
    }

    // ---- record results; flag uncertain rows into worklist ----
    if (nn == 0) {
        #pragma unroll
        for (int r = 0; r < 4; ++r) {
            bool flg = (m2[r] - m1[r]) < T_FLAG;
            rowinfo[w][quad * 4 + r] = i1[r] | (flg ? FLAGBIT : 0);
            if (flg) {
                int pos = atomicAdd(counter, 1);
                worklist[pos] = rowBase + quad * 4 + r;
            }
        }
    }
    __syncthreads();

    // ---- coalesced output + loss for certain rows (4 contiguous rows/pass) ----
    float lsum = 0.f;
    #pragma unroll
    for (int p = 0; p < 4; ++p) {
        int rl = p * 4 + quad;
        int info = rowinfo[w][rl];
        if (!(info & FLAGBIT)) {
            int j = info & 511;
            int kb = nn * 4;
            float q0 = cb[(kb + 0) * K + j];
            float q1 = cb[(kb + 1) * K + j];
            float q2 = cb[(kb + 2) * K + j];
            float q3 = cb[(kb + 3) * K + j];
            size_t row = (size_t)rowBase + rl;
            float4 xv = *(const float4*)(x + row * D + kb);
            float e0 = q0 - xv.x, e1 = q1 - xv.y, e2 = q2 - xv.z, e3 = q3 - xv.w;
            lsum += e0 * e0 + e1 * e1 + e2 * e2 + e3 * e3;
            *(float4*)(out + row * D + kb) = make_float4(q0, q1, q2, q3);
        }
    }
    #pragma unroll
    for (int off = 32; off > 0; off >>= 1) lsum += __shfl_down(lsum, off);
    if (lane == 0) wavesum[w] = lsum;
    __syncthreads();
    if (tid == 0) {
        double tot = 0.0;
        #pragma unroll
        for (int i = 0; i < 8; ++i) tot += (double)wavesum[i];
        atomicAdd(loss_acc, tot);
    }
}

// ---------------------------------------------------------------------------
// Kernel B: exact numpy-order rescan of flagged rows. One wave per row;
// lane handles 8 columns (j = lane + 64m). Bitwise-identical to round-2 path.
// ---------------------------------------------------------------------------
__global__ __launch_bounds__(256) void vq_rescan(const float* __restrict__ x,
                                                 const float* __restrict__ cb,
                                                 float* __restrict__ out,
                                                 double* __restrict__ loss_acc,
                                                 const int* __restrict__ counter,
                                                 const int* __restrict__ worklist) {
#pragma clang fp contract(off)
    const int lane = threadIdx.x & 63;
    const int gwave = blockIdx.x * 4 + (threadIdx.x >> 6);
    const int nwaves = gridDim.x * 4;
    const int count = *counter;

    for (int idx = gwave; idx < count; idx += nwaves) {
        int row = __builtin_amdgcn_readfirstlane(worklist[idx]);
        const float* xr = x + (size_t)row * D;

        // A = np.sum(x**2, axis=1): pairwise n=64 emulation (uniform math)
        float A0;
        {
            float rr[8];
            #pragma unroll
            for (int l = 0; l < 8; ++l) rr[l] = xr[l] * xr[l];
            #pragma unroll
            for (int m = 1; m < 8; ++m)
                #pragma unroll
                for (int l = 0; l < 8; ++l) {
                    float q = xr[8 * m + l] * xr[8 * m + l];
                    rr[l] = rr[l] + q;
                }
            A0 = ((rr[0] + rr[1]) + (rr[2] + rr[3])) + ((rr[4] + rr[5]) + (rr[6] + rr[7]));
        }

        float a[8], b[8];
        #pragma unroll
        for (int m = 0; m < 8; ++m) { a[m] = 0.f; b[m] = 0.f; }
        for (int k = 0; k < D; ++k) {
            float xk = xr[k];
            const float* crow = cb + k * K + lane;
            #pragma unroll
            for (int m = 0; m < 8; ++m) {
                float c = crow[m * 64];
                a[m] = fmaf(xk, c, a[m]);   // sequential-k fma chain
                b[m] = b[m] + c * c;        // numpy-order B (contract off)
            }
        }
        float db = INFINITY; int jb = 0x7fffffff;
        #pragma unroll
        for (int m = 0; m < 8; ++m) {
            float s = A0 + b[m];
            float t2 = 2.0f * a[m];
            float d = s - t2;               // fl(fl(A+B) - fl(2M))
            int j = lane + (m << 6);
            if (d < db) { db = d; jb = j; } // within-lane j ascending
        }
        for (int s = 1; s < 64; s <<= 1) {  // global first-index argmin
            float od = __shfl_xor(db, s);
            int oj = __shfl_xor(jb, s);
            if ((od < db) || (od == db && oj < jb)) { db = od; jb = oj; }
        }
        float q = cb[lane * K + jb];
        out[(size_t)row * D + lane] = q;
        float e = q - xr[lane];
        float ls = e * e;
        #pragma unroll
        for (int off = 32; off > 0; off >>= 1) ls += __shfl_down(ls, off);
        if (lane == 0) atomicAdd(loss_acc, (double)ls);
    }
}

__global__ void vq_finalize(const double* __restrict__ acc, float* __restrict__ out) {
    // loss = (1 + beta) * mean((q - x)^2), beta = 0.25
    out[NELEM] = (float)(acc[0] * (1.25 / (double)NELEM));
}

extern "C" void kernel_launch(void* const* d_in, const int* in_sizes, int n_in,
                              void* d_out, int out_size, void* d_ws, size_t ws_size,
                              hipStream_t stream) {
    const float* x  = (const float*)d_in[0];   // [32,64,64,64] fp32
    const float* cb = (const float*)d_in[1];   // [64,512] fp32
    float* out = (float*)d_out;                // [8388608] out + [1] loss
    double* loss_acc = (double*)d_ws;
    int* counter = (int*)((char*)d_ws + 8);
    int* worklist = (int*)((char*)d_ws + 16);

    hipMemsetAsync(d_ws, 0, 16, stream);
    vq_mfma<<<ROWS / 128, 512, 0, stream>>>(x, cb, out, loss_acc, counter, worklist);
    vq_rescan<<<512, 256, 0, stream>>>(x, cb, out, loss_acc, counter, worklist);
    vq_finalize<<<1, 1, 0, stream>>>(loss_acc, out);
}

// Round 5
// 176.681 us; speedup vs baseline: 1.5745x; 1.0566x over previous
//
#include <hip/hip_runtime.h>
#include <math.h>

#define D 64
#define K 512
#define ROWS 131072       // 32*64*64
#define NELEM (ROWS * D)  // 8388608
#define TGAP 64.0f        // flag threshold in 2^20-scaled units (= 6.1e-5 unscaled)
#define FLAGBIT (1 << 30)

typedef _Float16 half8 __attribute__((ext_vector_type(8)));
typedef float floatx4 __attribute__((ext_vector_type(4)));

// ws layout (bytes):
//   [0,8)            double loss accumulator
//   [4096,6144)      float  Bn20[512]    column norms * 2^20 (numpy order, exact scale)
//   [8192,73728)     _Float16 gH[32768]  hi B-fragments, MFMA fragment order
//   [73728,139264)   _Float16 gL[32768]  lo B-fragments
//   [139264,155648)  uint32 bitmap[4096] flagged-row bitmap (1 bit per row)

// ---------------------------------------------------------------------------
// Setup: codebook -> scaled fp16 hi/lo in B-fragment order (global), + norms.
// frag layout: half index = (((n>>4)*2 + (k>>5))*64 + ((k>>3)&3)*16 + (n&15))*8 + (k&7)
// ---------------------------------------------------------------------------
__global__ __launch_bounds__(512) void vq_setup(const float* __restrict__ cb,
                                                _Float16* __restrict__ gH,
                                                _Float16* __restrict__ gL,
                                                float* __restrict__ Bn) {
    int idx = blockIdx.x * 512 + threadIdx.x;   // 64 blocks x 512 = 32768
    int k = idx >> 9, n = idx & 511;
    float c = cb[idx];
    float t = c * 4096.0f;                      // 2^12, exact
    _Float16 ch = (_Float16)t;
    float r = t - (float)ch;                    // exact
    _Float16 cl = (_Float16)(r * 4096.0f);      // scale 2^24
    int off = (((n >> 4) * 2 + (k >> 5)) * 64 + ((k >> 3) & 3) * 16 + (n & 15)) * 8 + (k & 7);
    gH[off] = ch;
    gL[off] = cl;
    if (blockIdx.x == 0) {
#pragma clang fp contract(off)
        int j = threadIdx.x;
        float b = 0.f;
        for (int kk = 0; kk < D; ++kk) { float cc = cb[kk * K + j]; b = b + cc * cc; }
        Bn[j] = b * 0x1p20f;                    // exact power-of-2 scale
    }
}

// ---------------------------------------------------------------------------
// Main: MFMA filter, 256 thr = 4 waves, 64 rows/wave (4 tiles of 16).
// ---------------------------------------------------------------------------
__global__ __launch_bounds__(256, 2) void vq_main(const float* __restrict__ x,
                                                  const float* __restrict__ cb,
                                                  const _Float16* __restrict__ gH,
                                                  const _Float16* __restrict__ gL,
                                                  const float* __restrict__ Bn,
                                                  float* __restrict__ out,
                                                  double* __restrict__ loss_acc,
                                                  unsigned int* __restrict__ bitmap) {
    __shared__ float ldsB[K];
    __shared__ int rowinfo[4][64];
    __shared__ unsigned int flagbits[8];
    __shared__ float wavesum[4];

    const int tid = threadIdx.x;
    const int lane = tid & 63;
    const int w = tid >> 6;
    const int quad = lane >> 4;
    const int nn = lane & 15;

    ldsB[tid] = Bn[tid];
    ldsB[tid + 256] = Bn[tid + 256];
    if (tid < 8) flagbits[tid] = 0;

    const int rowBase = blockIdx.x * 256 + w * 64;

    // A-fragments: lane holds A[m=nn][k=quad*8+j] per k-half s, scaled hi/lo
    half8 xh[4][2], xl[4][2];
    #pragma unroll
    for (int tt = 0; tt < 4; ++tt) {
        #pragma unroll
        for (int s = 0; s < 2; ++s) {
            const float* xp = x + (size_t)(rowBase + tt * 16 + nn) * D + s * 32 + quad * 8;
            float4 v0 = *(const float4*)xp;
            float4 v1 = *(const float4*)(xp + 4);
            float vv[8] = {v0.x, v0.y, v0.z, v0.w, v1.x, v1.y, v1.z, v1.w};
            #pragma unroll
            for (int j = 0; j < 8; ++j) {
                float t = vv[j] * 256.0f;        // 2^8, exact
                _Float16 h = (_Float16)t;
                float r = t - (float)h;          // exact
                xh[tt][s][j] = h;
                xl[tt][s][j] = (_Float16)(r * 4096.0f);  // scale 2^20
            }
        }
    }
    __syncthreads();

    float m1[4][4], m2[4][4];
    int   i1[4][4];
    #pragma unroll
    for (int tt = 0; tt < 4; ++tt)
        #pragma unroll
        for (int r = 0; r < 4; ++r) { m1[tt][r] = INFINITY; m2[tt][r] = INFINITY; i1[tt][r] = 0; }

    const half8* bHp = (const half8*)gH;
    const half8* bLp = (const half8*)gL;

    #pragma unroll 2
    for (int t = 0; t < 32; ++t) {
        half8 bh0 = bHp[(t * 2 + 0) * 64 + lane];   // coalesced 16B/lane
        half8 bl0 = bLp[(t * 2 + 0) * 64 + lane];
        half8 bh1 = bHp[(t * 2 + 1) * 64 + lane];
        half8 bl1 = bLp[(t * 2 + 1) * 64 + lane];
        int col = t * 16 + nn;
        float Bj = ldsB[col];                       // B*2^20
        #pragma unroll
        for (int tt = 0; tt < 4; ++tt) {
            floatx4 a1 = {0.f, 0.f, 0.f, 0.f};
            floatx4 a2 = {0.f, 0.f, 0.f, 0.f};
            a2 = __builtin_amdgcn_mfma_f32_16x16x32_f16(xl[tt][0], bh0, a2, 0, 0, 0);
            a2 = __builtin_amdgcn_mfma_f32_16x16x32_f16(xh[tt][0], bl0, a2, 0, 0, 0);
            a1 = __builtin_amdgcn_mfma_f32_16x16x32_f16(xh[tt][0], bh0, a1, 0, 0, 0);
            a2 = __builtin_amdgcn_mfma_f32_16x16x32_f16(xl[tt][1], bh1, a2, 0, 0, 0);
            a2 = __builtin_amdgcn_mfma_f32_16x16x32_f16(xh[tt][1], bl1, a2, 0, 0, 0);
            a1 = __builtin_amdgcn_mfma_f32_16x16x32_f16(xh[tt][1], bh1, a1, 0, 0, 0);
            #pragma unroll
            for (int r = 0; r < 4; ++r) {
                float macc = fmaf(0x1p-12f, a2[r], a1[r]);   // M * 2^20
                float g = fmaf(-2.0f, macc, Bj);             // (B - 2M) * 2^20
                float old1 = m1[tt][r];
                bool c1 = g < old1;
                m2[tt][r] = fminf(fmaxf(g, old1), m2[tt][r]);
                m1[tt][r] = c1 ? g : old1;
                i1[tt][r] = c1 ? col : i1[tt][r];            // strict <, j ascending
            }
        }
    }

    // merge best-2 across the 16 col-lanes (butterfly over low 4 lane bits)
    #pragma unroll
    for (int dlt = 1; dlt < 16; dlt <<= 1) {
        #pragma unroll
        for (int tt = 0; tt < 4; ++tt)
            #pragma unroll
            for (int r = 0; r < 4; ++r) {
                float om1 = __shfl_xor(m1[tt][r], dlt);
                int   oi1 = __shfl_xor(i1[tt][r], dlt);
                float om2 = __shfl_xor(m2[tt][r], dlt);
                bool ofirst = (om1 < m1[tt][r]) || (om1 == m1[tt][r] && oi1 < i1[tt][r]);
                float l1   = ofirst ? m1[tt][r] : om1;
                float cand = ofirst ? om2 : m2[tt][r];
                m1[tt][r] = ofirst ? om1 : m1[tt][r];
                i1[tt][r] = ofirst ? oi1 : i1[tt][r];
                m2[tt][r] = fminf(cand, l1);
            }
    }

    // record results; flagged rows -> LDS bitmap bits
    if (nn == 0) {
        #pragma unroll
        for (int tt = 0; tt < 4; ++tt)
            #pragma unroll
            for (int r = 0; r < 4; ++r) {
                int rl = tt * 16 + quad * 4 + r;
                bool flg = (m2[tt][r] - m1[tt][r]) < TGAP;
                rowinfo[w][rl] = i1[tt][r] | (flg ? FLAGBIT : 0);
                if (flg) atomicOr(&flagbits[(w * 64 + rl) >> 5], 1u << ((w * 64 + rl) & 31));
            }
    }
    __syncthreads();
    if (tid < 8) bitmap[blockIdx.x * 8 + tid] = flagbits[tid];   // block-owned, no pre-zero

    // coalesced output + loss for certain rows
    float lsum = 0.f;
    #pragma unroll
    for (int tt = 0; tt < 4; ++tt) {
        #pragma unroll
        for (int p = 0; p < 4; ++p) {
            int rl = tt * 16 + p * 4 + quad;
            int info = rowinfo[w][rl];
            if (!(info & FLAGBIT)) {
                int j = info & 511;
                int kb = nn * 4;
                float q0 = cb[(kb + 0) * K + j];
                float q1 = cb[(kb + 1) * K + j];
                float q2 = cb[(kb + 2) * K + j];
                float q3 = cb[(kb + 3) * K + j];
                size_t row = (size_t)rowBase + rl;
                float4 xv = *(const float4*)(x + row * D + kb);
                float e0 = q0 - xv.x, e1 = q1 - xv.y, e2 = q2 - xv.z, e3 = q3 - xv.w;
                lsum += e0 * e0 + e1 * e1 + e2 * e2 + e3 * e3;
                *(float4*)(out + row * D + kb) = make_float4(q0, q1, q2, q3);
            }
        }
    }
    #pragma unroll
    for (int off = 32; off > 0; off >>= 1) lsum += __shfl_down(lsum, off);
    if (lane == 0) wavesum[w] = lsum;
    __syncthreads();
    if (tid == 0) {
        double tot = (double)wavesum[0] + (double)wavesum[1]
                   + (double)wavesum[2] + (double)wavesum[3];
        atomicAdd(loss_acc, tot);
    }
}

// ---------------------------------------------------------------------------
// Rescan: exact numpy-order pipeline for flagged rows. One wave per 64-row
// bitmap span; lane handles 8 columns (j = lane + 64m). One atomic per wave.
// ---------------------------------------------------------------------------
__global__ __launch_bounds__(256) void vq_rescan(const float* __restrict__ x,
                                                 const float* __restrict__ cb,
                                                 float* __restrict__ out,
                                                 double* __restrict__ loss_acc,
                                                 const unsigned int* __restrict__ bitmap) {
#pragma clang fp contract(off)
    const int lane = threadIdx.x & 63;
    const int gwave = blockIdx.x * 4 + (threadIdx.x >> 6);   // 0..2047

    unsigned int w0 = bitmap[gwave * 2 + 0];
    unsigned int w1 = bitmap[gwave * 2 + 1];
    unsigned long long mask = ((unsigned long long)w1 << 32) | w0;
    float wloss = 0.f;
    if (mask) {
        // numpy-order column norms for my 8 columns (hoisted across rows)
        float bn[8];
        #pragma unroll
        for (int m = 0; m < 8; ++m) bn[m] = 0.f;
        for (int k = 0; k < D; ++k) {
            const float* crow = cb + k * K + lane;
            #pragma unroll
            for (int m = 0; m < 8; ++m) {
                float c = crow[m * 64];
                bn[m] = bn[m] + c * c;
            }
        }
        while (mask) {
            int b = __builtin_ctzll(mask);
            mask &= mask - 1;
            int row = gwave * 64 + b;
            const float* xr = x + (size_t)row * D;
            // A = np.sum(x**2, axis=1): pairwise n=64 emulation
            float A0;
            {
                float rr[8];
                #pragma unroll
                for (int l = 0; l < 8; ++l) rr[l] = xr[l] * xr[l];
                #pragma unroll
                for (int m = 1; m < 8; ++m)
                    #pragma unroll
                    for (int l = 0; l < 8; ++l) {
                        float q = xr[8 * m + l] * xr[8 * m + l];
                        rr[l] = rr[l] + q;
                    }
                A0 = ((rr[0] + rr[1]) + (rr[2] + rr[3])) + ((rr[4] + rr[5]) + (rr[6] + rr[7]));
            }
            float a[8];
            #pragma unroll
            for (int m = 0; m < 8; ++m) a[m] = 0.f;
            for (int k = 0; k < D; ++k) {
                float xk = xr[k];
                const float* crow = cb + k * K + lane;
                #pragma unroll
                for (int m = 0; m < 8; ++m)
                    a[m] = fmaf(xk, crow[m * 64], a[m]);   // sequential-k fma chain
            }
            float db = INFINITY; int jb = 0x7fffffff;
            #pragma unroll
            for (int m = 0; m < 8; ++m) {
                float s = A0 + bn[m];
                float t2 = 2.0f * a[m];
                float d = s - t2;                  // fl(fl(A+B) - fl(2M))
                int j = lane + (m << 6);
                if (d < db) { db = d; jb = j; }
            }
            for (int s = 1; s < 64; s <<= 1) {     // first-index global argmin
                float od = __shfl_xor(db, s);
                int oj = __shfl_xor(jb, s);
                if ((od < db) || (od == db && oj < jb)) { db = od; jb = oj; }
            }
            float q = cb[lane * K + jb];
            out[(size_t)row * D + lane] = q;
            float e = q - xr[lane];
            wloss += e * e;
        }
    }
    #pragma unroll
    for (int off = 32; off > 0; off >>= 1) wloss += __shfl_down(wloss, off);
    if (lane == 0 && wloss != 0.f) atomicAdd(loss_acc, (double)wloss);
}

__global__ void vq_finalize(const double* __restrict__ acc, float* __restrict__ out) {
    // loss = (1 + beta) * mean((q - x)^2), beta = 0.25
    out[NELEM] = (float)(acc[0] * (1.25 / (double)NELEM));
}

extern "C" void kernel_launch(void* const* d_in, const int* in_sizes, int n_in,
                              void* d_out, int out_size, void* d_ws, size_t ws_size,
                              hipStream_t stream) {
    const float* x  = (const float*)d_in[0];   // [32,64,64,64] fp32
    const float* cb = (const float*)d_in[1];   // [64,512] fp32
    float* out = (float*)d_out;                // [8388608] out + [1] loss
    double* loss_acc = (double*)d_ws;
    float* Bn        = (float*)((char*)d_ws + 4096);
    _Float16* gH     = (_Float16*)((char*)d_ws + 8192);
    _Float16* gL     = (_Float16*)((char*)d_ws + 73728);
    unsigned int* bm = (unsigned int*)((char*)d_ws + 139264);

    hipMemsetAsync(d_ws, 0, 16, stream);
    vq_setup<<<64, 512, 0, stream>>>(cb, gH, gL, Bn);
    vq_main<<<ROWS / 256, 256, 0, stream>>>(x, cb, gH, gL, Bn, out, loss_acc, bm);
    vq_rescan<<<512, 256, 0, stream>>>(x, cb, out, loss_acc, bm);
    vq_finalize<<<1, 1, 0, stream>>>(loss_acc, out);
}